// Round 8
// baseline (799.167 us; speedup 1.0000x reference)
//
#include <hip/hip_runtime.h>
#include <cstdint>

// Problem constants
#define BB 2
#define TT 2048
#define DM 2048
#define NH 16
#define HD 128
#define QKVN 6144   // 3*DM

using f32x4   = __attribute__((ext_vector_type(4))) float;
using bf16x8  = __attribute__((ext_vector_type(8))) __bf16;
using ushort8 = __attribute__((ext_vector_type(8))) unsigned short;

static __device__ __forceinline__ unsigned short f2bf(float f) {
    uint32_t u = __builtin_bit_cast(uint32_t, f);
    u += 0x7FFFu + ((u >> 16) & 1u);          // RNE
    return (unsigned short)(u >> 16);
}
static __device__ __forceinline__ float bf2f(unsigned short h) {
    return __builtin_bit_cast(float, ((uint32_t)h) << 16);
}

#define GLOAD16(SRC, DST)                                               \
    __builtin_amdgcn_global_load_lds(                                   \
        (const __attribute__((address_space(1))) void*)(SRC),           \
        (__attribute__((address_space(3))) void*)(DST), 16, 0, 0)

// ---------------------------------------------------------------------------
// 1) elementwise fp32 -> bf16 hi/lo split (for x)
// ---------------------------------------------------------------------------
__global__ __launch_bounds__(256) void k_split(const float* __restrict__ in,
                                               unsigned short* __restrict__ hi,
                                               unsigned short* __restrict__ lo,
                                               int n4) {
    int i = blockIdx.x * 256 + threadIdx.x;
    if (i >= n4) return;
    float4 v = reinterpret_cast<const float4*>(in)[i];
    ushort4 h, l;
    h.x = f2bf(v.x); l.x = f2bf(v.x - bf2f(h.x));
    h.y = f2bf(v.y); l.y = f2bf(v.y - bf2f(h.y));
    h.z = f2bf(v.z); l.z = f2bf(v.z - bf2f(h.z));
    h.w = f2bf(v.w); l.w = f2bf(v.w - bf2f(h.w));
    reinterpret_cast<ushort4*>(hi)[i] = h;
    reinterpret_cast<ushort4*>(lo)[i] = l;
}

// ---------------------------------------------------------------------------
// 2) W [K,N] fp32 -> Wt hi [N,K] bf16  (transpose, hi only)
// ---------------------------------------------------------------------------
__global__ __launch_bounds__(256) void k_tsplit(const float* __restrict__ W,
                                                unsigned short* __restrict__ th,
                                                int K, int N) {
    __shared__ float tile[32][33];
    int bn = blockIdx.x * 32, bk = blockIdx.y * 32;
    int tx = threadIdx.x, ty = threadIdx.y;   // 32 x 8
#pragma unroll
    for (int r = 0; r < 4; r++)
        tile[ty + 8 * r][tx] = W[(size_t)(bk + ty + 8 * r) * N + bn + tx];
    __syncthreads();
#pragma unroll
    for (int r = 0; r < 4; r++) {
        float v = tile[tx][ty + 8 * r];
        int row = bn + ty + 8 * r, col = bk + tx;
        th[(size_t)row * K + col] = f2bf(v);
    }
}

// ---------------------------------------------------------------------------
// 3) GEMM v5 (A-direct):  C[M,N] = (Ah[+Al])[M,K] * Bh^T
//    BM=256, BN=128, BK=64, 8 waves (4m x 2n), 64x64/wave, 4x4 acc.
//    ONLY B staged in LDS (dbuf 2x16KB, XOR-swizzled); A fragments loaded
//    global->VGPR directly (A-frag layout == row-major global layout) into
//    static banks a0 (kstep0) / a1 (kstep1), one tile lookahead, issued in
//    ph2/ph3 after their WAR readers. Manual wait: counted vmcnt(2*AV) at
//    tile top (waits B staging only; A lookahead stays in flight). Compiler
//    auto-waitcnt covers reg A-loads and B ds_reads.
//    SPLIT=1: 2-term split-A (hi+lo). SPLIT=0: plain bf16 A.
//    EPI 0: write C bf16 hi. EPI 1: write fp32 C + bias.
// ---------------------------------------------------------------------------
template <int EPI, int SPLIT>
__global__ __launch_bounds__(512, 2) void k_gemm(
    const unsigned short* __restrict__ Ah, const unsigned short* __restrict__ Al,
    const unsigned short* __restrict__ Bh,
    unsigned short* __restrict__ Ch,
    float* __restrict__ Cf, const float* __restrict__ bias,
    int M, int N, int K) {
    __shared__ __align__(16) unsigned short sBh[2][8192];    // 128 rows x 64

    // T1: bijective XCD swizzle (both grids have nwg % 8 == 0)
    const int nwg = gridDim.x * gridDim.y;
    const int L = blockIdx.y * gridDim.x + blockIdx.x;
    const int logical = (L & 7) * (nwg >> 3) + (L >> 3);
    const int bx = logical % gridDim.x, by = logical / gridDim.x;

    const int tid = threadIdx.x;
    const int wave = tid >> 6, lane = tid & 63;
    const int g = lane >> 4, r16 = lane & 15;
    const int arow0 = by * 256, bcol0 = bx * 128;
    const int wr = (wave >> 1) * 64, wc = (wave & 1) * 64;
    const int sw8 = r16 & 7;

    // B staging: thread covers row = i*64 + (tid>>3), slot = tid&7, pre-swizzled src
    const int srow = tid >> 3;
    const int scol = ((tid & 7) ^ (srow & 7)) << 3;

    // A fragment bases: row = arow0 + wr + m*16 + r16, col base g*8
    size_t aBase[4];
#pragma unroll
    for (int m = 0; m < 4; m++)
        aBase[m] = (size_t)(arow0 + wr + m * 16 + r16) * K + g * 8;

    f32x4 acc[4][4];
#pragma unroll
    for (int m = 0; m < 4; m++)
#pragma unroll
        for (int n = 0; n < 4; n++) acc[m][n] = (f32x4){0.f, 0.f, 0.f, 0.f};

    const int NT = K >> 6;

    auto stageB = [&](int buf, int tk) {
        const size_t kof = (size_t)tk * 64 + scol;
#pragma unroll
        for (int i = 0; i < 2; i++)
            GLOAD16(Bh + (size_t)(bcol0 + i * 64 + srow) * K + kof,
                    &sBh[buf][(i * 512 + tid) * 8]);
    };
    auto rdB = [&](int buf, int n, int slot) {
        int ro = (wc + n * 16 + r16) * 64 + ((slot ^ sw8) << 3);
        return __builtin_bit_cast(bf16x8, *(const ushort8*)&sBh[buf][ro]);
    };

    bf16x8 a0h[4], a0l[4], a1h[4], a1l[4];
    auto loadA0 = [&](int kcol) {   // kstep0 frags of K-tile at col kcol
#pragma unroll
        for (int m = 0; m < 4; m++) {
            a0h[m] = __builtin_bit_cast(bf16x8, *(const ushort8*)(Ah + aBase[m] + kcol));
            if (SPLIT) a0l[m] = __builtin_bit_cast(bf16x8, *(const ushort8*)(Al + aBase[m] + kcol));
        }
    };
    auto loadA1 = [&](int kcol) {   // kstep1 frags
#pragma unroll
        for (int m = 0; m < 4; m++) {
            a1h[m] = __builtin_bit_cast(bf16x8, *(const ushort8*)(Ah + aBase[m] + kcol + 32));
            if (SPLIT) a1l[m] = __builtin_bit_cast(bf16x8, *(const ushort8*)(Al + aBase[m] + kcol + 32));
        }
    };

    // prologue: B tile0 staged first (oldest in vmcnt FIFO), then A tile0
    stageB(0, 0);
    loadA0(0);
    loadA1(0);

    int cur = 0;
    for (int t = 0; t < NT; ++t) {
        // wait B staging for tile t (leave the 2*AV A-loads of banks in flight)
        if (SPLIT) asm volatile("s_waitcnt vmcnt(16)" ::: "memory");
        else       asm volatile("s_waitcnt vmcnt(8)" ::: "memory");
        __builtin_amdgcn_s_barrier();
        const bool pf = (t + 1 < NT);
        const int nb = cur ^ 1;
        const int nkcol = (t + 1) * 64;

        // ---- ph0: all 8 B frag reads + stage B(t+1); MFMA m01 x k0
        bf16x8 bh0[4], bh1[4];
#pragma unroll
        for (int n = 0; n < 4; n++) bh0[n] = rdB(cur, n, g);
#pragma unroll
        for (int n = 0; n < 4; n++) bh1[n] = rdB(cur, n, 4 + g);
        if (pf) stageB(nb, t + 1);
        __builtin_amdgcn_sched_barrier(0);
        __builtin_amdgcn_s_setprio(1);
#pragma unroll
        for (int m = 0; m < 2; m++)
#pragma unroll
            for (int n = 0; n < 4; n++) {
                acc[m][n] = __builtin_amdgcn_mfma_f32_16x16x32_bf16(a0h[m], bh0[n], acc[m][n], 0, 0, 0);
                if (SPLIT)
                    acc[m][n] = __builtin_amdgcn_mfma_f32_16x16x32_bf16(a0l[m], bh0[n], acc[m][n], 0, 0, 0);
            }
        __builtin_amdgcn_s_setprio(0);
        __builtin_amdgcn_sched_barrier(0);

        // ---- ph1: MFMA m23 x k0 (last readers of a0)
        __builtin_amdgcn_s_setprio(1);
#pragma unroll
        for (int m = 2; m < 4; m++)
#pragma unroll
            for (int n = 0; n < 4; n++) {
                acc[m][n] = __builtin_amdgcn_mfma_f32_16x16x32_bf16(a0h[m], bh0[n], acc[m][n], 0, 0, 0);
                if (SPLIT)
                    acc[m][n] = __builtin_amdgcn_mfma_f32_16x16x32_bf16(a0l[m], bh0[n], acc[m][n], 0, 0, 0);
            }
        __builtin_amdgcn_s_setprio(0);
        __builtin_amdgcn_sched_barrier(0);

        // ---- ph2: issue a0 bank loads for t+1 (a0 free now); MFMA m01 x k1
        if (pf) loadA0(nkcol);
        __builtin_amdgcn_sched_barrier(0);
        __builtin_amdgcn_s_setprio(1);
#pragma unroll
        for (int m = 0; m < 2; m++)
#pragma unroll
            for (int n = 0; n < 4; n++) {
                acc[m][n] = __builtin_amdgcn_mfma_f32_16x16x32_bf16(a1h[m], bh1[n], acc[m][n], 0, 0, 0);
                if (SPLIT)
                    acc[m][n] = __builtin_amdgcn_mfma_f32_16x16x32_bf16(a1l[m], bh1[n], acc[m][n], 0, 0, 0);
            }
        __builtin_amdgcn_s_setprio(0);
        __builtin_amdgcn_sched_barrier(0);

        // ---- ph3: MFMA m23 x k1, THEN issue a1 bank loads for t+1 (WAR)
        __builtin_amdgcn_s_setprio(1);
#pragma unroll
        for (int m = 2; m < 4; m++)
#pragma unroll
            for (int n = 0; n < 4; n++) {
                acc[m][n] = __builtin_amdgcn_mfma_f32_16x16x32_bf16(a1h[m], bh1[n], acc[m][n], 0, 0, 0);
                if (SPLIT)
                    acc[m][n] = __builtin_amdgcn_mfma_f32_16x16x32_bf16(a1l[m], bh1[n], acc[m][n], 0, 0, 0);
            }
        __builtin_amdgcn_s_setprio(0);
        __builtin_amdgcn_sched_barrier(0);
        if (pf) loadA1(nkcol);
        cur ^= 1;
    }

#pragma unroll
    for (int m = 0; m < 4; m++)
#pragma unroll
        for (int n = 0; n < 4; n++) {
            int col = bcol0 + wc + n * 16 + r16;
#pragma unroll
            for (int j = 0; j < 4; j++) {
                int row = arow0 + wr + m * 16 + g * 4 + j;
                float v = acc[m][n][j];
                if (EPI == 0) {
                    Ch[(size_t)row * N + col] = f2bf(v);
                } else {
                    Cf[(size_t)row * N + col] = v + bias[col];
                }
            }
        }
}

// ---------------------------------------------------------------------------
// 4) RoPE in place on qkv hi (cols 0..4095 = q,k), one block per (b,t) row
// ---------------------------------------------------------------------------
__global__ __launch_bounds__(256) void k_rope(unsigned short* __restrict__ qh) {
    __shared__ float row[4096];
    __shared__ float cs[64], sn[64];
    const int rb = blockIdx.x;        // b*T + t
    const int t = rb & (TT - 1);
    const int tid = threadIdx.x;
    if (tid < 64) {
        float invf = 1.0f / powf(10000.0f, (float)tid * (1.0f / 64.0f));
        float s, c;
        sincosf((float)t * invf, &s, &c);
        cs[tid] = c; sn[tid] = s;
    }
    const size_t base = (size_t)rb * QKVN;
#pragma unroll
    for (int i = 0; i < 2; i++) {
        int c0 = (tid + i * 256) * 8;
        ushort8 h = *(const ushort8*)&qh[base + c0];
#pragma unroll
        for (int e = 0; e < 8; e++) row[c0 + e] = bf2f(h[e]);
    }
    __syncthreads();
#pragma unroll
    for (int i = 0; i < 2; i++) {
        int c0 = (tid + i * 256) * 8;
        int d0 = c0 & 127;
        ushort8 h;
#pragma unroll
        for (int e = 0; e < 8; e++) {
            int c = c0 + e, d = d0 + e;
            float x = row[c];
            float xr = (d < 64) ? -row[c + 64] : row[c - 64];
            float v = x * cs[d & 63] + xr * sn[d & 63];
            h[e] = f2bf(v);
        }
        *(ushort8*)&qh[base + c0] = h;
    }
}

// ---------------------------------------------------------------------------
// 5) extract V^T per head: vt[bh][d][t] = bf16(qkv[b,t, 4096 + h*128 + d])
// ---------------------------------------------------------------------------
__global__ __launch_bounds__(128) void k_vt(const unsigned short* __restrict__ qkvh,
                                            unsigned short* __restrict__ vt) {
    const int bh = blockIdx.x;    // 0..31
    const int tc = blockIdx.y;    // 0..31 (chunk of 64 t's)
    const int d = threadIdx.x;    // 0..127
    const int b = bh >> 4, h = bh & 15;
    unsigned short buf[64];
    const size_t src0 = ((size_t)(b * TT + tc * 64)) * QKVN + 4096 + h * 128 + d;
#pragma unroll
    for (int ttt = 0; ttt < 64; ttt++) buf[ttt] = qkvh[src0 + (size_t)ttt * QKVN];
    const size_t dst = ((size_t)bh * 128 + d) * TT + tc * 64;
#pragma unroll
    for (int i = 0; i < 8; i++)
        *(ushort8*)&vt[dst + i * 8] = *(const ushort8*)&buf[i * 8];
}

// ---------------------------------------------------------------------------
// 6) causal flash attention (QBLK=64, KVBLK=64, dbuf staging, XCD remap,
//    heavy-qb-first). Epilogue writes bf16 hi only (GEMM2 is plain bf16 now).
// ---------------------------------------------------------------------------
__global__ __launch_bounds__(256) void k_flash(const unsigned short* __restrict__ qkvh,
                                               const unsigned short* __restrict__ vt,
                                               unsigned short* __restrict__ aoh) {
    __shared__ unsigned short sK[2][64 * 128];
    __shared__ unsigned short sV[2][128 * 64];
    __shared__ unsigned short sP[4][16 * 64];

    const int L = blockIdx.y * gridDim.x + blockIdx.x;
    const int logical = (L & 7) * 128 + (L >> 3);
    const int bh = logical >> 5;
    const int qb = 31 - (logical & 31);
    const int b = bh >> 4, h = bh & 15;

    const int tid = threadIdx.x, wave = tid >> 6, lane = tid & 63;
    const int g = lane >> 4, r16 = lane & 15;
    const float scale = 0.08838834764831845f;   // 1/sqrt(128)

    bf16x8 qf[4];
    {
        const int qrow = qb * 64 + wave * 16 + r16;
        const size_t qbase = ((size_t)(b * TT) + qrow) * QKVN + h * 128;
#pragma unroll
        for (int kk = 0; kk < 4; kk++) {
            ushort8 u = *(const ushort8*)&qkvh[qbase + kk * 32 + g * 8];
            ushort8 o;
#pragma unroll
            for (int e = 0; e < 8; e++) o[e] = f2bf(bf2f(u[e]) * scale);
            qf[kk] = __builtin_bit_cast(bf16x8, o);
        }
    }

    f32x4 oacc[8];
#pragma unroll
    for (int n = 0; n < 8; n++) oacc[n] = (f32x4){0.f, 0.f, 0.f, 0.f};
    float mrun[4], lrun[4];
#pragma unroll
    for (int j = 0; j < 4; j++) { mrun[j] = -1e30f; lrun[j] = 0.f; }

    const int k_row_st = wave * 4 + (lane >> 4);    // + i*16 ; slot = lane&15
    const int v_row_st = wave * 8 + (lane >> 3);    // + i*32 ; slot = lane&7
    const int lidx = wave * 512 + lane * 8;

    auto stage = [&](int buf, int kb) {
#pragma unroll
        for (int i = 0; i < 4; i++) {
            int krow = i * 16 + k_row_st;
            int kcol = ((lane & 15) ^ (krow & 7)) << 3;
            GLOAD16(qkvh + ((size_t)(b * TT + kb * 64 + krow)) * QKVN + 2048 + h * 128 + kcol,
                    &sK[buf][i * 2048 + lidx]);
            int vrow = i * 32 + v_row_st;
            int vcol = ((lane & 7) ^ (vrow & 7)) << 3;
            GLOAD16(vt + ((size_t)bh * 128 + vrow) * TT + kb * 64 + vcol,
                    &sV[buf][i * 2048 + lidx]);
        }
    };

    const int nkb = qb + 1;
    int cur = 0;
    stage(0, 0);

    for (int kb = 0; kb < nkb; kb++) {
        __syncthreads();
        if (kb + 1 < nkb) stage(cur ^ 1, kb + 1);

        f32x4 sacc[4];
#pragma unroll
        for (int n = 0; n < 4; n++) sacc[n] = (f32x4){0.f, 0.f, 0.f, 0.f};
#pragma unroll
        for (int n = 0; n < 4; n++) {
            const int krow = n * 16 + r16;
            const int rbase = krow * 128;
            const int sw = krow & 7;
#pragma unroll
            for (int kk = 0; kk < 4; kk++) {
                int slot = (kk * 4 + g) ^ sw;
                bf16x8 kf = __builtin_bit_cast(bf16x8, *(const ushort8*)&sK[cur][rbase + slot * 8]);
                sacc[n] = __builtin_amdgcn_mfma_f32_16x16x32_bf16(qf[kk], kf, sacc[n], 0, 0, 0);
            }
        }

        const int key0 = kb * 64;
#pragma unroll
        for (int j = 0; j < 4; j++) {
            const int prow = g * 4 + j;
            const int qg = qb * 64 + wave * 16 + prow;
            float s0 = sacc[0][j], s1 = sacc[1][j], s2 = sacc[2][j], s3 = sacc[3][j];
            if (kb == qb) {
                if (key0 + r16 > qg)      s0 = -1e30f;
                if (key0 + 16 + r16 > qg) s1 = -1e30f;
                if (key0 + 32 + r16 > qg) s2 = -1e30f;
                if (key0 + 48 + r16 > qg) s3 = -1e30f;
            }
            float tmax = fmaxf(fmaxf(s0, s1), fmaxf(s2, s3));
#pragma unroll
            for (int off = 8; off >= 1; off >>= 1) tmax = fmaxf(tmax, __shfl_xor(tmax, off));
            float mnew = fmaxf(mrun[j], tmax);
            float corr = __expf(mrun[j] - mnew);
            float p0 = __expf(s0 - mnew), p1 = __expf(s1 - mnew);
            float p2 = __expf(s2 - mnew), p3 = __expf(s3 - mnew);
            float rs = (p0 + p1) + (p2 + p3);
#pragma unroll
            for (int off = 8; off >= 1; off >>= 1) rs += __shfl_xor(rs, off);
            lrun[j] = lrun[j] * corr + rs;
            mrun[j] = mnew;
#pragma unroll
            for (int n = 0; n < 8; n++) oacc[n][j] *= corr;
            const int pb = prow * 64, sw = prow & 7, e = r16 & 7, hi2 = (r16 >> 3);
            sP[wave][pb + (((0 + hi2) ^ sw) << 3) + e] = f2bf(p0);
            sP[wave][pb + (((2 + hi2) ^ sw) << 3) + e] = f2bf(p1);
            sP[wave][pb + (((4 + hi2) ^ sw) << 3) + e] = f2bf(p2);
            sP[wave][pb + (((6 + hi2) ^ sw) << 3) + e] = f2bf(p3);
        }

#pragma unroll
        for (int kk = 0; kk < 2; kk++) {
            const int slot = (kk * 4 + g) ^ (r16 & 7);
            bf16x8 pf = __builtin_bit_cast(bf16x8, *(const ushort8*)&sP[wave][r16 * 64 + slot * 8]);
#pragma unroll
            for (int n = 0; n < 8; n++) {
                const int d = n * 16 + r16;
                bf16x8 vf = __builtin_bit_cast(bf16x8, *(const ushort8*)&sV[cur][d * 64 + slot * 8]);
                oacc[n] = __builtin_amdgcn_mfma_f32_16x16x32_bf16(pf, vf, oacc[n], 0, 0, 0);
            }
        }
        cur ^= 1;
    }

#pragma unroll
    for (int j = 0; j < 4; j++) {
        float inv = 1.0f / lrun[j];
        int qg = qb * 64 + wave * 16 + g * 4 + j;
        size_t obase = ((size_t)(b * TT) + qg) * DM + h * 128;
#pragma unroll
        for (int n = 0; n < 8; n++)
            aoh[obase + n * 16 + r16] = f2bf(oacc[n][j] * inv);
    }
}

// ---------------------------------------------------------------------------
extern "C" void kernel_launch(void* const* d_in, const int* in_sizes, int n_in,
                              void* d_out, int out_size, void* d_ws, size_t ws_size,
                              hipStream_t stream) {
    const float* x = (const float*)d_in[0];
    const float* Wqkv = (const float*)d_in[1];
    const float* Wproj = (const float*)d_in[2];
    const float* bproj = (const float*)d_in[3];
    // d_in[4] = mask (causal structure implemented directly)

    uint8_t* w = (uint8_t*)d_ws;
    auto alloc = [&](size_t bytes) { uint8_t* p = w; w += bytes; return p; };
    unsigned short* xh   = (unsigned short*)alloc(8388608ull * 2);   // x hi
    unsigned short* xl   = (unsigned short*)alloc(8388608ull * 2);   // x lo
    unsigned short* wqh  = (unsigned short*)alloc(12582912ull * 2);  // WqkvT hi [6144][2048]
    unsigned short* wph  = (unsigned short*)alloc(4194304ull * 2);   // WprojT hi [2048][2048]
    unsigned short* qkvh = (unsigned short*)alloc(25165824ull * 2);  // qkv hi [4096][6144]
    unsigned short* vtp  = (unsigned short*)alloc(8388608ull * 2);   // V^T [32][128][2048]
    unsigned short* aoh  = (unsigned short*)alloc(8388608ull * 2);   // attn out hi [4096][2048]

    k_split<<<dim3(8192), dim3(256), 0, stream>>>(x, xh, xl, 2097152);
    k_tsplit<<<dim3(192, 64), dim3(32, 8), 0, stream>>>(Wqkv, wqh, 2048, 6144);
    k_tsplit<<<dim3(64, 64), dim3(32, 8), 0, stream>>>(Wproj, wph, 2048, 2048);
    k_gemm<0, 1><<<dim3(48, 16), dim3(512), 0, stream>>>(xh, xl, wqh,
                                                         qkvh, nullptr, nullptr,
                                                         4096, 6144, 2048);
    k_rope<<<dim3(4096), dim3(256), 0, stream>>>(qkvh);
    k_vt<<<dim3(32, 32), dim3(128), 0, stream>>>(qkvh, vtp);
    k_flash<<<dim3(32, 32), dim3(256), 0, stream>>>(qkvh, vtp, aoh);
    k_gemm<1, 0><<<dim3(16, 16), dim3(512), 0, stream>>>(aoh, nullptr, wph,
                                                         nullptr, (float*)d_out, bproj,
                                                         4096, 2048, 2048);
}

// Round 9
// 548.456 us; speedup vs baseline: 1.4571x; 1.4571x over previous
//
#include <hip/hip_runtime.h>
#include <cstdint>

// Problem constants
#define BB 2
#define TT 2048
#define DM 2048
#define NH 16
#define HD 128
#define QKVN 6144   // 3*DM

using f32x4   = __attribute__((ext_vector_type(4))) float;
using bf16x8  = __attribute__((ext_vector_type(8))) __bf16;
using ushort8 = __attribute__((ext_vector_type(8))) unsigned short;

static __device__ __forceinline__ unsigned short f2bf(float f) {
    uint32_t u = __builtin_bit_cast(uint32_t, f);
    u += 0x7FFFu + ((u >> 16) & 1u);          // RNE
    return (unsigned short)(u >> 16);
}
static __device__ __forceinline__ float bf2f(unsigned short h) {
    return __builtin_bit_cast(float, ((uint32_t)h) << 16);
}

#define GLOAD16(SRC, DST)                                               \
    __builtin_amdgcn_global_load_lds(                                   \
        (const __attribute__((address_space(1))) void*)(SRC),           \
        (__attribute__((address_space(3))) void*)(DST), 16, 0, 0)

// ---------------------------------------------------------------------------
// 1) elementwise fp32 -> bf16 hi/lo split (for x)
// ---------------------------------------------------------------------------
__global__ __launch_bounds__(256) void k_split(const float* __restrict__ in,
                                               unsigned short* __restrict__ hi,
                                               unsigned short* __restrict__ lo,
                                               int n4) {
    int i = blockIdx.x * 256 + threadIdx.x;
    if (i >= n4) return;
    float4 v = reinterpret_cast<const float4*>(in)[i];
    ushort4 h, l;
    h.x = f2bf(v.x); l.x = f2bf(v.x - bf2f(h.x));
    h.y = f2bf(v.y); l.y = f2bf(v.y - bf2f(h.y));
    h.z = f2bf(v.z); l.z = f2bf(v.z - bf2f(h.z));
    h.w = f2bf(v.w); l.w = f2bf(v.w - bf2f(h.w));
    reinterpret_cast<ushort4*>(hi)[i] = h;
    reinterpret_cast<ushort4*>(lo)[i] = l;
}

// ---------------------------------------------------------------------------
// 2) W [K,N] fp32 -> Wt hi [N,K] bf16  (transpose, hi only)
// ---------------------------------------------------------------------------
__global__ __launch_bounds__(256) void k_tsplit(const float* __restrict__ W,
                                                unsigned short* __restrict__ th,
                                                int K, int N) {
    __shared__ float tile[32][33];
    int bn = blockIdx.x * 32, bk = blockIdx.y * 32;
    int tx = threadIdx.x, ty = threadIdx.y;   // 32 x 8
#pragma unroll
    for (int r = 0; r < 4; r++)
        tile[ty + 8 * r][tx] = W[(size_t)(bk + ty + 8 * r) * N + bn + tx];
    __syncthreads();
#pragma unroll
    for (int r = 0; r < 4; r++) {
        float v = tile[tx][ty + 8 * r];
        int row = bn + ty + 8 * r, col = bk + tx;
        th[(size_t)row * K + col] = f2bf(v);
    }
}

// ---------------------------------------------------------------------------
// 3) split-bf16 GEMM (R6-proven 4-phase LDS-staged structure):
//    C[M,N] = (Ah[+Al])[M,K] * Bh^T.  BM=256, BN=128, BK=64, 8 waves
//    (4m x 2n), 64x64/wave, 4x4 acc. Double-buffered LDS, XOR-swizzled rows
//    (pre-swizzled global src for global_load_lds, same involution on read),
//    4-phase/K-tile: issue next chunk's ds_reads + staging gloads, counted
//    lgkmcnt (1 chunk lookahead in flight), setprio(1) around 16/8-MFMA
//    cluster, s_barrier per phase, vmcnt(0) only at tile top.
//    SPLIT=1: 2-term split-A (hi+lo staged, 160 KB LDS, lgkmcnt(4)).
//    SPLIT=0: plain bf16 A (hi only, 96 KB LDS, lgkmcnt(2)).
//    EPI 0: write C bf16 hi.  EPI 1: write fp32 C + bias.
// ---------------------------------------------------------------------------
template <int EPI, int SPLIT>
__global__ __launch_bounds__(512, 2) void k_gemm(
    const unsigned short* __restrict__ Ah, const unsigned short* __restrict__ Al,
    const unsigned short* __restrict__ Bh,
    unsigned short* __restrict__ Ch,
    float* __restrict__ Cf, const float* __restrict__ bias,
    int M, int N, int K) {
    __shared__ __align__(16) unsigned short sAh[2][16384];   // 256 rows x 64
    __shared__ __align__(16) unsigned short sAl[SPLIT ? 2 : 1][SPLIT ? 16384 : 8];
    __shared__ __align__(16) unsigned short sBh[2][8192];    // 128 rows x 64

    // T1: bijective XCD swizzle (both grids have nwg % 8 == 0)
    const int nwg = gridDim.x * gridDim.y;
    const int L = blockIdx.y * gridDim.x + blockIdx.x;
    const int logical = (L & 7) * (nwg >> 3) + (L >> 3);
    const int bx = logical % gridDim.x, by = logical / gridDim.x;

    const int tid = threadIdx.x;
    const int wave = tid >> 6, lane = tid & 63;
    const int g = lane >> 4, r16 = lane & 15;
    const int arow0 = by * 256, bcol0 = bx * 128;
    const int wr = (wave >> 1) * 64, wc = (wave & 1) * 64;
    const int sw8 = r16 & 7;                   // fragment-read swizzle

    // staging: thread covers row = i*64 + (tid>>3), slot = tid&7 (pre-swizzled src)
    const int srow = tid >> 3;
    const int scol = ((tid & 7) ^ (srow & 7)) << 3;

    f32x4 acc[4][4];
#pragma unroll
    for (int m = 0; m < 4; m++)
#pragma unroll
        for (int n = 0; n < 4; n++) acc[m][n] = (f32x4){0.f, 0.f, 0.f, 0.f};

    const int NT = K >> 6;

    auto stageA_hi = [&](int buf, int tk) {
        const size_t kof = (size_t)tk * 64 + scol;
#pragma unroll
        for (int i = 0; i < 4; i++)
            GLOAD16(Ah + (size_t)(arow0 + i * 64 + srow) * K + kof,
                    &sAh[buf][(i * 512 + tid) * 8]);
    };
    auto stageA_lo = [&](int buf, int tk) {
        const size_t kof = (size_t)tk * 64 + scol;
#pragma unroll
        for (int i = 0; i < 4; i++)
            GLOAD16(Al + (size_t)(arow0 + i * 64 + srow) * K + kof,
                    &sAl[buf][(i * 512 + tid) * 8]);
    };
    auto stageB = [&](int buf, int tk) {
        const size_t kof = (size_t)tk * 64 + scol;
#pragma unroll
        for (int i = 0; i < 2; i++)
            GLOAD16(Bh + (size_t)(bcol0 + i * 64 + srow) * K + kof,
                    &sBh[buf][(i * 512 + tid) * 8]);
    };

    auto rdA = [&](int buf, int m, int co, bf16x8& h, bf16x8& l) {
        int ro = (wr + m * 16 + r16) * 64 + co;
        h = __builtin_bit_cast(bf16x8, *(const ushort8*)&sAh[buf][ro]);
        if (SPLIT) l = __builtin_bit_cast(bf16x8, *(const ushort8*)&sAl[buf][ro]);
    };
    auto rdB = [&](int buf, int n, int co) {
        int ro = (wc + n * 16 + r16) * 64 + co;
        return __builtin_bit_cast(bf16x8, *(const ushort8*)&sBh[buf][ro]);
    };

    // prologue: stage tile 0
    stageA_hi(0, 0);
    if (SPLIT) stageA_lo(0, 0);
    stageB(0, 0);

    int cur = 0;
    for (int t = 0; t < NT; ++t) {
        asm volatile("s_waitcnt vmcnt(0)" ::: "memory");   // tile-t staging landed
        __builtin_amdgcn_s_barrier();                      // all reads of buf^1 retired
        const bool pf = (t + 1 < NT);
        const int nb = cur ^ 1;
        const int co0 = (g ^ sw8) << 3, co1 = ((4 + g) ^ sw8) << 3;

        bf16x8 ah0[4], al0[4], bh0[4], ah1[4], al1[4], bh1[4];

        // ---- ph0: issue chunk0 (B k0 + A m01 k0) + chunk1 (A m23 k0)
#pragma unroll
        for (int n = 0; n < 4; n++) bh0[n] = rdB(cur, n, co0);
        rdA(cur, 0, co0, ah0[0], al0[0]);
        rdA(cur, 1, co0, ah0[1], al0[1]);
        __builtin_amdgcn_sched_barrier(0);
        rdA(cur, 2, co0, ah0[2], al0[2]);
        rdA(cur, 3, co0, ah0[3], al0[3]);
        __builtin_amdgcn_sched_barrier(0);
        if (pf) stageA_hi(nb, t + 1);
        if (SPLIT) asm volatile("s_waitcnt lgkmcnt(4)" ::: "memory");
        else       asm volatile("s_waitcnt lgkmcnt(2)" ::: "memory");
        __builtin_amdgcn_sched_barrier(0);
        __builtin_amdgcn_s_setprio(1);
#pragma unroll
        for (int m = 0; m < 2; m++)
#pragma unroll
            for (int n = 0; n < 4; n++) {
                acc[m][n] = __builtin_amdgcn_mfma_f32_16x16x32_bf16(ah0[m], bh0[n], acc[m][n], 0, 0, 0);
                if (SPLIT)
                    acc[m][n] = __builtin_amdgcn_mfma_f32_16x16x32_bf16(al0[m], bh0[n], acc[m][n], 0, 0, 0);
            }
        __builtin_amdgcn_s_setprio(0);
        __builtin_amdgcn_s_barrier();

        // ---- ph1: issue chunk2 (A m01 k1)
        rdA(cur, 0, co1, ah1[0], al1[0]);
        rdA(cur, 1, co1, ah1[1], al1[1]);
        __builtin_amdgcn_sched_barrier(0);
        if (SPLIT) { if (pf) stageA_lo(nb, t + 1); }
        if (SPLIT) asm volatile("s_waitcnt lgkmcnt(4)" ::: "memory");
        else       asm volatile("s_waitcnt lgkmcnt(2)" ::: "memory");
        __builtin_amdgcn_sched_barrier(0);
        __builtin_amdgcn_s_setprio(1);
#pragma unroll
        for (int m = 2; m < 4; m++)
#pragma unroll
            for (int n = 0; n < 4; n++) {
                acc[m][n] = __builtin_amdgcn_mfma_f32_16x16x32_bf16(ah0[m], bh0[n], acc[m][n], 0, 0, 0);
                if (SPLIT)
                    acc[m][n] = __builtin_amdgcn_mfma_f32_16x16x32_bf16(al0[m], bh0[n], acc[m][n], 0, 0, 0);
            }
        __builtin_amdgcn_s_setprio(0);
        __builtin_amdgcn_s_barrier();

        // ---- ph2: issue B k1 then chunk3 (A m23 k1)
#pragma unroll
        for (int n = 0; n < 4; n++) bh1[n] = rdB(cur, n, co1);
        __builtin_amdgcn_sched_barrier(0);
        rdA(cur, 2, co1, ah1[2], al1[2]);
        rdA(cur, 3, co1, ah1[3], al1[3]);
        __builtin_amdgcn_sched_barrier(0);
        if (pf) stageB(nb, t + 1);
        if (SPLIT) asm volatile("s_waitcnt lgkmcnt(4)" ::: "memory");
        else       asm volatile("s_waitcnt lgkmcnt(2)" ::: "memory");
        __builtin_amdgcn_sched_barrier(0);
        __builtin_amdgcn_s_setprio(1);
#pragma unroll
        for (int m = 0; m < 2; m++)
#pragma unroll
            for (int n = 0; n < 4; n++) {
                acc[m][n] = __builtin_amdgcn_mfma_f32_16x16x32_bf16(ah1[m], bh1[n], acc[m][n], 0, 0, 0);
                if (SPLIT)
                    acc[m][n] = __builtin_amdgcn_mfma_f32_16x16x32_bf16(al1[m], bh1[n], acc[m][n], 0, 0, 0);
            }
        __builtin_amdgcn_s_setprio(0);
        __builtin_amdgcn_s_barrier();

        // ---- ph3
        asm volatile("s_waitcnt lgkmcnt(0)" ::: "memory");  // chunk3 done
        __builtin_amdgcn_sched_barrier(0);
        __builtin_amdgcn_s_setprio(1);
#pragma unroll
        for (int m = 2; m < 4; m++)
#pragma unroll
            for (int n = 0; n < 4; n++) {
                acc[m][n] = __builtin_amdgcn_mfma_f32_16x16x32_bf16(ah1[m], bh1[n], acc[m][n], 0, 0, 0);
                if (SPLIT)
                    acc[m][n] = __builtin_amdgcn_mfma_f32_16x16x32_bf16(al1[m], bh1[n], acc[m][n], 0, 0, 0);
            }
        __builtin_amdgcn_s_setprio(0);
        cur ^= 1;
    }

#pragma unroll
    for (int m = 0; m < 4; m++)
#pragma unroll
        for (int n = 0; n < 4; n++) {
            int col = bcol0 + wc + n * 16 + r16;
#pragma unroll
            for (int j = 0; j < 4; j++) {
                int row = arow0 + wr + m * 16 + g * 4 + j;
                float v = acc[m][n][j];
                if (EPI == 0) {
                    Ch[(size_t)row * N + col] = f2bf(v);
                } else {
                    Cf[(size_t)row * N + col] = v + bias[col];
                }
            }
        }
}

// ---------------------------------------------------------------------------
// 4) RoPE in place on qkv hi (cols 0..4095 = q,k), one block per (b,t) row
// ---------------------------------------------------------------------------
__global__ __launch_bounds__(256) void k_rope(unsigned short* __restrict__ qh) {
    __shared__ float row[4096];
    __shared__ float cs[64], sn[64];
    const int rb = blockIdx.x;        // b*T + t
    const int t = rb & (TT - 1);
    const int tid = threadIdx.x;
    if (tid < 64) {
        float invf = 1.0f / powf(10000.0f, (float)tid * (1.0f / 64.0f));
        float s, c;
        sincosf((float)t * invf, &s, &c);
        cs[tid] = c; sn[tid] = s;
    }
    const size_t base = (size_t)rb * QKVN;
#pragma unroll
    for (int i = 0; i < 2; i++) {
        int c0 = (tid + i * 256) * 8;
        ushort8 h = *(const ushort8*)&qh[base + c0];
#pragma unroll
        for (int e = 0; e < 8; e++) row[c0 + e] = bf2f(h[e]);
    }
    __syncthreads();
#pragma unroll
    for (int i = 0; i < 2; i++) {
        int c0 = (tid + i * 256) * 8;
        int d0 = c0 & 127;
        ushort8 h;
#pragma unroll
        for (int e = 0; e < 8; e++) {
            int c = c0 + e, d = d0 + e;
            float x = row[c];
            float xr = (d < 64) ? -row[c + 64] : row[c - 64];
            float v = x * cs[d & 63] + xr * sn[d & 63];
            h[e] = f2bf(v);
        }
        *(ushort8*)&qh[base + c0] = h;
    }
}

// ---------------------------------------------------------------------------
// 5) extract V^T per head: vt[bh][d][t] = bf16(qkv[b,t, 4096 + h*128 + d])
// ---------------------------------------------------------------------------
__global__ __launch_bounds__(128) void k_vt(const unsigned short* __restrict__ qkvh,
                                            unsigned short* __restrict__ vt) {
    const int bh = blockIdx.x;    // 0..31
    const int tc = blockIdx.y;    // 0..31 (chunk of 64 t's)
    const int d = threadIdx.x;    // 0..127
    const int b = bh >> 4, h = bh & 15;
    unsigned short buf[64];
    const size_t src0 = ((size_t)(b * TT + tc * 64)) * QKVN + 4096 + h * 128 + d;
#pragma unroll
    for (int ttt = 0; ttt < 64; ttt++) buf[ttt] = qkvh[src0 + (size_t)ttt * QKVN];
    const size_t dst = ((size_t)bh * 128 + d) * TT + tc * 64;
#pragma unroll
    for (int i = 0; i < 8; i++)
        *(ushort8*)&vt[dst + i * 8] = *(const ushort8*)&buf[i * 8];
}

// ---------------------------------------------------------------------------
// 6) causal flash attention (QBLK=64, KVBLK=64, dbuf staging, XCD remap,
//    heavy-qb-first). Epilogue writes bf16 hi only (GEMM2 is plain bf16).
// ---------------------------------------------------------------------------
__global__ __launch_bounds__(256) void k_flash(const unsigned short* __restrict__ qkvh,
                                               const unsigned short* __restrict__ vt,
                                               unsigned short* __restrict__ aoh) {
    __shared__ unsigned short sK[2][64 * 128];
    __shared__ unsigned short sV[2][128 * 64];
    __shared__ unsigned short sP[4][16 * 64];

    const int L = blockIdx.y * gridDim.x + blockIdx.x;
    const int logical = (L & 7) * 128 + (L >> 3);
    const int bh = logical >> 5;
    const int qb = 31 - (logical & 31);
    const int b = bh >> 4, h = bh & 15;

    const int tid = threadIdx.x, wave = tid >> 6, lane = tid & 63;
    const int g = lane >> 4, r16 = lane & 15;
    const float scale = 0.08838834764831845f;   // 1/sqrt(128)

    bf16x8 qf[4];
    {
        const int qrow = qb * 64 + wave * 16 + r16;
        const size_t qbase = ((size_t)(b * TT) + qrow) * QKVN + h * 128;
#pragma unroll
        for (int kk = 0; kk < 4; kk++) {
            ushort8 u = *(const ushort8*)&qkvh[qbase + kk * 32 + g * 8];
            ushort8 o;
#pragma unroll
            for (int e = 0; e < 8; e++) o[e] = f2bf(bf2f(u[e]) * scale);
            qf[kk] = __builtin_bit_cast(bf16x8, o);
        }
    }

    f32x4 oacc[8];
#pragma unroll
    for (int n = 0; n < 8; n++) oacc[n] = (f32x4){0.f, 0.f, 0.f, 0.f};
    float mrun[4], lrun[4];
#pragma unroll
    for (int j = 0; j < 4; j++) { mrun[j] = -1e30f; lrun[j] = 0.f; }

    const int k_row_st = wave * 4 + (lane >> 4);    // + i*16 ; slot = lane&15
    const int v_row_st = wave * 8 + (lane >> 3);    // + i*32 ; slot = lane&7
    const int lidx = wave * 512 + lane * 8;

    auto stage = [&](int buf, int kb) {
#pragma unroll
        for (int i = 0; i < 4; i++) {
            int krow = i * 16 + k_row_st;
            int kcol = ((lane & 15) ^ (krow & 7)) << 3;
            GLOAD16(qkvh + ((size_t)(b * TT + kb * 64 + krow)) * QKVN + 2048 + h * 128 + kcol,
                    &sK[buf][i * 2048 + lidx]);
            int vrow = i * 32 + v_row_st;
            int vcol = ((lane & 7) ^ (vrow & 7)) << 3;
            GLOAD16(vt + ((size_t)bh * 128 + vrow) * TT + kb * 64 + vcol,
                    &sV[buf][i * 2048 + lidx]);
        }
    };

    const int nkb = qb + 1;
    int cur = 0;
    stage(0, 0);

    for (int kb = 0; kb < nkb; kb++) {
        __syncthreads();
        if (kb + 1 < nkb) stage(cur ^ 1, kb + 1);

        f32x4 sacc[4];
#pragma unroll
        for (int n = 0; n < 4; n++) sacc[n] = (f32x4){0.f, 0.f, 0.f, 0.f};
#pragma unroll
        for (int n = 0; n < 4; n++) {
            const int krow = n * 16 + r16;
            const int rbase = krow * 128;
            const int sw = krow & 7;
#pragma unroll
            for (int kk = 0; kk < 4; kk++) {
                int slot = (kk * 4 + g) ^ sw;
                bf16x8 kf = __builtin_bit_cast(bf16x8, *(const ushort8*)&sK[cur][rbase + slot * 8]);
                sacc[n] = __builtin_amdgcn_mfma_f32_16x16x32_bf16(qf[kk], kf, sacc[n], 0, 0, 0);
            }
        }

        const int key0 = kb * 64;
#pragma unroll
        for (int j = 0; j < 4; j++) {
            const int prow = g * 4 + j;
            const int qg = qb * 64 + wave * 16 + prow;
            float s0 = sacc[0][j], s1 = sacc[1][j], s2 = sacc[2][j], s3 = sacc[3][j];
            if (kb == qb) {
                if (key0 + r16 > qg)      s0 = -1e30f;
                if (key0 + 16 + r16 > qg) s1 = -1e30f;
                if (key0 + 32 + r16 > qg) s2 = -1e30f;
                if (key0 + 48 + r16 > qg) s3 = -1e30f;
            }
            float tmax = fmaxf(fmaxf(s0, s1), fmaxf(s2, s3));
#pragma unroll
            for (int off = 8; off >= 1; off >>= 1) tmax = fmaxf(tmax, __shfl_xor(tmax, off));
            float mnew = fmaxf(mrun[j], tmax);
            float corr = __expf(mrun[j] - mnew);
            float p0 = __expf(s0 - mnew), p1 = __expf(s1 - mnew);
            float p2 = __expf(s2 - mnew), p3 = __expf(s3 - mnew);
            float rs = (p0 + p1) + (p2 + p3);
#pragma unroll
            for (int off = 8; off >= 1; off >>= 1) rs += __shfl_xor(rs, off);
            lrun[j] = lrun[j] * corr + rs;
            mrun[j] = mnew;
#pragma unroll
            for (int n = 0; n < 8; n++) oacc[n][j] *= corr;
            const int pb = prow * 64, sw = prow & 7, e = r16 & 7, hi2 = (r16 >> 3);
            sP[wave][pb + (((0 + hi2) ^ sw) << 3) + e] = f2bf(p0);
            sP[wave][pb + (((2 + hi2) ^ sw) << 3) + e] = f2bf(p1);
            sP[wave][pb + (((4 + hi2) ^ sw) << 3) + e] = f2bf(p2);
            sP[wave][pb + (((6 + hi2) ^ sw) << 3) + e] = f2bf(p3);
        }

#pragma unroll
        for (int kk = 0; kk < 2; kk++) {
            const int slot = (kk * 4 + g) ^ (r16 & 7);
            bf16x8 pf = __builtin_bit_cast(bf16x8, *(const ushort8*)&sP[wave][r16 * 64 + slot * 8]);
#pragma unroll
            for (int n = 0; n < 8; n++) {
                const int d = n * 16 + r16;
                bf16x8 vf = __builtin_bit_cast(bf16x8, *(const ushort8*)&sV[cur][d * 64 + slot * 8]);
                oacc[n] = __builtin_amdgcn_mfma_f32_16x16x32_bf16(pf, vf, oacc[n], 0, 0, 0);
            }
        }
        cur ^= 1;
    }

#pragma unroll
    for (int j = 0; j < 4; j++) {
        float inv = 1.0f / lrun[j];
        int qg = qb * 64 + wave * 16 + g * 4 + j;
        size_t obase = ((size_t)(b * TT) + qg) * DM + h * 128;
#pragma unroll
        for (int n = 0; n < 8; n++)
            aoh[obase + n * 16 + r16] = f2bf(oacc[n][j] * inv);
    }
}

// ---------------------------------------------------------------------------
extern "C" void kernel_launch(void* const* d_in, const int* in_sizes, int n_in,
                              void* d_out, int out_size, void* d_ws, size_t ws_size,
                              hipStream_t stream) {
    const float* x = (const float*)d_in[0];
    const float* Wqkv = (const float*)d_in[1];
    const float* Wproj = (const float*)d_in[2];
    const float* bproj = (const float*)d_in[3];
    // d_in[4] = mask (causal structure implemented directly)

    uint8_t* w = (uint8_t*)d_ws;
    auto alloc = [&](size_t bytes) { uint8_t* p = w; w += bytes; return p; };
    unsigned short* xh   = (unsigned short*)alloc(8388608ull * 2);   // x hi
    unsigned short* xl   = (unsigned short*)alloc(8388608ull * 2);   // x lo
    unsigned short* wqh  = (unsigned short*)alloc(12582912ull * 2);  // WqkvT hi [6144][2048]
    unsigned short* wph  = (unsigned short*)alloc(4194304ull * 2);   // WprojT hi [2048][2048]
    unsigned short* qkvh = (unsigned short*)alloc(25165824ull * 2);  // qkv hi [4096][6144]
    unsigned short* vtp  = (unsigned short*)alloc(8388608ull * 2);   // V^T [32][128][2048]
    unsigned short* aoh  = (unsigned short*)alloc(8388608ull * 2);   // attn out hi [4096][2048]

    k_split<<<dim3(8192), dim3(256), 0, stream>>>(x, xh, xl, 2097152);
    k_tsplit<<<dim3(192, 64), dim3(32, 8), 0, stream>>>(Wqkv, wqh, 2048, 6144);
    k_tsplit<<<dim3(64, 64), dim3(32, 8), 0, stream>>>(Wproj, wph, 2048, 2048);
    k_gemm<0, 1><<<dim3(48, 16), dim3(512), 0, stream>>>(xh, xl, wqh,
                                                         qkvh, nullptr, nullptr,
                                                         4096, 6144, 2048);
    k_rope<<<dim3(4096), dim3(256), 0, stream>>>(qkvh);
    k_vt<<<dim3(32, 32), dim3(128), 0, stream>>>(qkvh, vtp);
    k_flash<<<dim3(32, 32), dim3(256), 0, stream>>>(qkvh, vtp, aoh);
    k_gemm<1, 0><<<dim3(16, 16), dim3(512), 0, stream>>>(aoh, nullptr, wph,
                                                         nullptr, (float*)d_out, bproj,
                                                         4096, 2048, 2048);
}

// Round 10
// 511.897 us; speedup vs baseline: 1.5612x; 1.0714x over previous
//
#include <hip/hip_runtime.h>
#include <cstdint>

// Problem constants
#define BB 2
#define TT 2048
#define DM 2048
#define NH 16
#define HD 128
#define QKVN 6144   // 3*DM

using f32x4   = __attribute__((ext_vector_type(4))) float;
using bf16x8  = __attribute__((ext_vector_type(8))) __bf16;
using ushort8 = __attribute__((ext_vector_type(8))) unsigned short;

static __device__ __forceinline__ unsigned short f2bf(float f) {
    uint32_t u = __builtin_bit_cast(uint32_t, f);
    u += 0x7FFFu + ((u >> 16) & 1u);          // RNE
    return (unsigned short)(u >> 16);
}
static __device__ __forceinline__ float bf2f(unsigned short h) {
    return __builtin_bit_cast(float, ((uint32_t)h) << 16);
}

#define GLOAD16(SRC, DST)                                               \
    __builtin_amdgcn_global_load_lds(                                   \
        (const __attribute__((address_space(1))) void*)(SRC),           \
        (__attribute__((address_space(3))) void*)(DST), 16, 0, 0)

// ---------------------------------------------------------------------------
// 1) elementwise fp32 -> bf16 cast (x). Plain GEMM1 validated path: the
//    split-A lo term's contribution to the FINAL output is ~0.001 sd (damped
//    through softmax), comparable to the aoh bf16 rounding already present.
// ---------------------------------------------------------------------------
__global__ __launch_bounds__(256) void k_split(const float* __restrict__ in,
                                               unsigned short* __restrict__ hi,
                                               int n4) {
    int i = blockIdx.x * 256 + threadIdx.x;
    if (i >= n4) return;
    float4 v = reinterpret_cast<const float4*>(in)[i];
    ushort4 h;
    h.x = f2bf(v.x);
    h.y = f2bf(v.y);
    h.z = f2bf(v.z);
    h.w = f2bf(v.w);
    reinterpret_cast<ushort4*>(hi)[i] = h;
}

// ---------------------------------------------------------------------------
// 2) W [K,N] fp32 -> Wt hi [N,K] bf16  (transpose, hi only)
// ---------------------------------------------------------------------------
__global__ __launch_bounds__(256) void k_tsplit(const float* __restrict__ W,
                                                unsigned short* __restrict__ th,
                                                int K, int N) {
    __shared__ float tile[32][33];
    int bn = blockIdx.x * 32, bk = blockIdx.y * 32;
    int tx = threadIdx.x, ty = threadIdx.y;   // 32 x 8
#pragma unroll
    for (int r = 0; r < 4; r++)
        tile[ty + 8 * r][tx] = W[(size_t)(bk + ty + 8 * r) * N + bn + tx];
    __syncthreads();
#pragma unroll
    for (int r = 0; r < 4; r++) {
        float v = tile[tx][ty + 8 * r];
        int row = bn + ty + 8 * r, col = bk + tx;
        th[(size_t)row * K + col] = f2bf(v);
    }
}

// ---------------------------------------------------------------------------
// 3) bf16 GEMM (R9-proven 4-phase LDS-staged structure):
//    C[M,N] = (Ah[+Al])[M,K] * Bh^T.  BM=256, BN=128, BK=64, 8 waves
//    (4m x 2n), 64x64/wave, 4x4 acc. Double-buffered LDS, XOR-swizzled rows
//    (pre-swizzled global src for global_load_lds, same involution on read),
//    4-phase/K-tile: issue next chunk's ds_reads + staging gloads, counted
//    lgkmcnt (1 chunk lookahead in flight), setprio(1) around MFMA cluster,
//    s_barrier per phase, vmcnt(0) only at tile top.
//    SPLIT=1: 2-term split-A (160 KB LDS, lgkmcnt(4)) — available, unused.
//    SPLIT=0: plain bf16 A (96 KB LDS, lgkmcnt(2)) — both GEMMs now.
//    EPI 0: write C bf16 hi.  EPI 1: write fp32 C + bias.
// ---------------------------------------------------------------------------
template <int EPI, int SPLIT>
__global__ __launch_bounds__(512, 2) void k_gemm(
    const unsigned short* __restrict__ Ah, const unsigned short* __restrict__ Al,
    const unsigned short* __restrict__ Bh,
    unsigned short* __restrict__ Ch,
    float* __restrict__ Cf, const float* __restrict__ bias,
    int M, int N, int K) {
    __shared__ __align__(16) unsigned short sAh[2][16384];   // 256 rows x 64
    __shared__ __align__(16) unsigned short sAl[SPLIT ? 2 : 1][SPLIT ? 16384 : 8];
    __shared__ __align__(16) unsigned short sBh[2][8192];    // 128 rows x 64

    // T1: bijective XCD swizzle (both grids have nwg % 8 == 0)
    const int nwg = gridDim.x * gridDim.y;
    const int L = blockIdx.y * gridDim.x + blockIdx.x;
    const int logical = (L & 7) * (nwg >> 3) + (L >> 3);
    const int bx = logical % gridDim.x, by = logical / gridDim.x;

    const int tid = threadIdx.x;
    const int wave = tid >> 6, lane = tid & 63;
    const int g = lane >> 4, r16 = lane & 15;
    const int arow0 = by * 256, bcol0 = bx * 128;
    const int wr = (wave >> 1) * 64, wc = (wave & 1) * 64;
    const int sw8 = r16 & 7;                   // fragment-read swizzle

    // staging: thread covers row = i*64 + (tid>>3), slot = tid&7 (pre-swizzled src)
    const int srow = tid >> 3;
    const int scol = ((tid & 7) ^ (srow & 7)) << 3;

    f32x4 acc[4][4];
#pragma unroll
    for (int m = 0; m < 4; m++)
#pragma unroll
        for (int n = 0; n < 4; n++) acc[m][n] = (f32x4){0.f, 0.f, 0.f, 0.f};

    const int NT = K >> 6;

    auto stageA_hi = [&](int buf, int tk) {
        const size_t kof = (size_t)tk * 64 + scol;
#pragma unroll
        for (int i = 0; i < 4; i++)
            GLOAD16(Ah + (size_t)(arow0 + i * 64 + srow) * K + kof,
                    &sAh[buf][(i * 512 + tid) * 8]);
    };
    auto stageA_lo = [&](int buf, int tk) {
        const size_t kof = (size_t)tk * 64 + scol;
#pragma unroll
        for (int i = 0; i < 4; i++)
            GLOAD16(Al + (size_t)(arow0 + i * 64 + srow) * K + kof,
                    &sAl[buf][(i * 512 + tid) * 8]);
    };
    auto stageB = [&](int buf, int tk) {
        const size_t kof = (size_t)tk * 64 + scol;
#pragma unroll
        for (int i = 0; i < 2; i++)
            GLOAD16(Bh + (size_t)(bcol0 + i * 64 + srow) * K + kof,
                    &sBh[buf][(i * 512 + tid) * 8]);
    };

    auto rdA = [&](int buf, int m, int co, bf16x8& h, bf16x8& l) {
        int ro = (wr + m * 16 + r16) * 64 + co;
        h = __builtin_bit_cast(bf16x8, *(const ushort8*)&sAh[buf][ro]);
        if (SPLIT) l = __builtin_bit_cast(bf16x8, *(const ushort8*)&sAl[buf][ro]);
    };
    auto rdB = [&](int buf, int n, int co) {
        int ro = (wc + n * 16 + r16) * 64 + co;
        return __builtin_bit_cast(bf16x8, *(const ushort8*)&sBh[buf][ro]);
    };

    // prologue: stage tile 0
    stageA_hi(0, 0);
    if (SPLIT) stageA_lo(0, 0);
    stageB(0, 0);

    int cur = 0;
    for (int t = 0; t < NT; ++t) {
        asm volatile("s_waitcnt vmcnt(0)" ::: "memory");   // tile-t staging landed
        __builtin_amdgcn_s_barrier();                      // all reads of buf^1 retired
        const bool pf = (t + 1 < NT);
        const int nb = cur ^ 1;
        const int co0 = (g ^ sw8) << 3, co1 = ((4 + g) ^ sw8) << 3;

        bf16x8 ah0[4], al0[4], bh0[4], ah1[4], al1[4], bh1[4];

        // ---- ph0: issue chunk0 (B k0 + A m01 k0) + chunk1 (A m23 k0)
#pragma unroll
        for (int n = 0; n < 4; n++) bh0[n] = rdB(cur, n, co0);
        rdA(cur, 0, co0, ah0[0], al0[0]);
        rdA(cur, 1, co0, ah0[1], al0[1]);
        __builtin_amdgcn_sched_barrier(0);
        rdA(cur, 2, co0, ah0[2], al0[2]);
        rdA(cur, 3, co0, ah0[3], al0[3]);
        __builtin_amdgcn_sched_barrier(0);
        if (pf) stageA_hi(nb, t + 1);
        if (SPLIT) asm volatile("s_waitcnt lgkmcnt(4)" ::: "memory");
        else       asm volatile("s_waitcnt lgkmcnt(2)" ::: "memory");
        __builtin_amdgcn_sched_barrier(0);
        __builtin_amdgcn_s_setprio(1);
#pragma unroll
        for (int m = 0; m < 2; m++)
#pragma unroll
            for (int n = 0; n < 4; n++) {
                acc[m][n] = __builtin_amdgcn_mfma_f32_16x16x32_bf16(ah0[m], bh0[n], acc[m][n], 0, 0, 0);
                if (SPLIT)
                    acc[m][n] = __builtin_amdgcn_mfma_f32_16x16x32_bf16(al0[m], bh0[n], acc[m][n], 0, 0, 0);
            }
        __builtin_amdgcn_s_setprio(0);
        __builtin_amdgcn_s_barrier();

        // ---- ph1: issue chunk2 (A m01 k1)
        rdA(cur, 0, co1, ah1[0], al1[0]);
        rdA(cur, 1, co1, ah1[1], al1[1]);
        __builtin_amdgcn_sched_barrier(0);
        if (SPLIT) { if (pf) stageA_lo(nb, t + 1); }
        if (SPLIT) asm volatile("s_waitcnt lgkmcnt(4)" ::: "memory");
        else       asm volatile("s_waitcnt lgkmcnt(2)" ::: "memory");
        __builtin_amdgcn_sched_barrier(0);
        __builtin_amdgcn_s_setprio(1);
#pragma unroll
        for (int m = 2; m < 4; m++)
#pragma unroll
            for (int n = 0; n < 4; n++) {
                acc[m][n] = __builtin_amdgcn_mfma_f32_16x16x32_bf16(ah0[m], bh0[n], acc[m][n], 0, 0, 0);
                if (SPLIT)
                    acc[m][n] = __builtin_amdgcn_mfma_f32_16x16x32_bf16(al0[m], bh0[n], acc[m][n], 0, 0, 0);
            }
        __builtin_amdgcn_s_setprio(0);
        __builtin_amdgcn_s_barrier();

        // ---- ph2: issue B k1 then chunk3 (A m23 k1)
#pragma unroll
        for (int n = 0; n < 4; n++) bh1[n] = rdB(cur, n, co1);
        __builtin_amdgcn_sched_barrier(0);
        rdA(cur, 2, co1, ah1[2], al1[2]);
        rdA(cur, 3, co1, ah1[3], al1[3]);
        __builtin_amdgcn_sched_barrier(0);
        if (pf) stageB(nb, t + 1);
        if (SPLIT) asm volatile("s_waitcnt lgkmcnt(4)" ::: "memory");
        else       asm volatile("s_waitcnt lgkmcnt(2)" ::: "memory");
        __builtin_amdgcn_sched_barrier(0);
        __builtin_amdgcn_s_setprio(1);
#pragma unroll
        for (int m = 0; m < 2; m++)
#pragma unroll
            for (int n = 0; n < 4; n++) {
                acc[m][n] = __builtin_amdgcn_mfma_f32_16x16x32_bf16(ah1[m], bh1[n], acc[m][n], 0, 0, 0);
                if (SPLIT)
                    acc[m][n] = __builtin_amdgcn_mfma_f32_16x16x32_bf16(al1[m], bh1[n], acc[m][n], 0, 0, 0);
            }
        __builtin_amdgcn_s_setprio(0);
        __builtin_amdgcn_s_barrier();

        // ---- ph3
        asm volatile("s_waitcnt lgkmcnt(0)" ::: "memory");  // chunk3 done
        __builtin_amdgcn_sched_barrier(0);
        __builtin_amdgcn_s_setprio(1);
#pragma unroll
        for (int m = 2; m < 4; m++)
#pragma unroll
            for (int n = 0; n < 4; n++) {
                acc[m][n] = __builtin_amdgcn_mfma_f32_16x16x32_bf16(ah1[m], bh1[n], acc[m][n], 0, 0, 0);
                if (SPLIT)
                    acc[m][n] = __builtin_amdgcn_mfma_f32_16x16x32_bf16(al1[m], bh1[n], acc[m][n], 0, 0, 0);
            }
        __builtin_amdgcn_s_setprio(0);
        cur ^= 1;
    }

#pragma unroll
    for (int m = 0; m < 4; m++)
#pragma unroll
        for (int n = 0; n < 4; n++) {
            int col = bcol0 + wc + n * 16 + r16;
#pragma unroll
            for (int j = 0; j < 4; j++) {
                int row = arow0 + wr + m * 16 + g * 4 + j;
                float v = acc[m][n][j];
                if (EPI == 0) {
                    Ch[(size_t)row * N + col] = f2bf(v);
                } else {
                    Cf[(size_t)row * N + col] = v + bias[col];
                }
            }
        }
}

// ---------------------------------------------------------------------------
// 4) RoPE in place on qkv hi (cols 0..4095 = q,k), one block per (b,t) row
// ---------------------------------------------------------------------------
__global__ __launch_bounds__(256) void k_rope(unsigned short* __restrict__ qh) {
    __shared__ float row[4096];
    __shared__ float cs[64], sn[64];
    const int rb = blockIdx.x;        // b*T + t
    const int t = rb & (TT - 1);
    const int tid = threadIdx.x;
    if (tid < 64) {
        float invf = 1.0f / powf(10000.0f, (float)tid * (1.0f / 64.0f));
        float s, c;
        sincosf((float)t * invf, &s, &c);
        cs[tid] = c; sn[tid] = s;
    }
    const size_t base = (size_t)rb * QKVN;
#pragma unroll
    for (int i = 0; i < 2; i++) {
        int c0 = (tid + i * 256) * 8;
        ushort8 h = *(const ushort8*)&qh[base + c0];
#pragma unroll
        for (int e = 0; e < 8; e++) row[c0 + e] = bf2f(h[e]);
    }
    __syncthreads();
#pragma unroll
    for (int i = 0; i < 2; i++) {
        int c0 = (tid + i * 256) * 8;
        int d0 = c0 & 127;
        ushort8 h;
#pragma unroll
        for (int e = 0; e < 8; e++) {
            int c = c0 + e, d = d0 + e;
            float x = row[c];
            float xr = (d < 64) ? -row[c + 64] : row[c - 64];
            float v = x * cs[d & 63] + xr * sn[d & 63];
            h[e] = f2bf(v);
        }
        *(ushort8*)&qh[base + c0] = h;
    }
}

// ---------------------------------------------------------------------------
// 5) extract V^T per head: vt[bh][d][t] = bf16(qkv[b,t, 4096 + h*128 + d])
// ---------------------------------------------------------------------------
__global__ __launch_bounds__(128) void k_vt(const unsigned short* __restrict__ qkvh,
                                            unsigned short* __restrict__ vt) {
    const int bh = blockIdx.x;    // 0..31
    const int tc = blockIdx.y;    // 0..31 (chunk of 64 t's)
    const int d = threadIdx.x;    // 0..127
    const int b = bh >> 4, h = bh & 15;
    unsigned short buf[64];
    const size_t src0 = ((size_t)(b * TT + tc * 64)) * QKVN + 4096 + h * 128 + d;
#pragma unroll
    for (int ttt = 0; ttt < 64; ttt++) buf[ttt] = qkvh[src0 + (size_t)ttt * QKVN];
    const size_t dst = ((size_t)bh * 128 + d) * TT + tc * 64;
#pragma unroll
    for (int i = 0; i < 8; i++)
        *(ushort8*)&vt[dst + i * 8] = *(const ushort8*)&buf[i * 8];
}

// ---------------------------------------------------------------------------
// 6) causal flash attention (QBLK=64, KVBLK=64, dbuf staging, XCD remap,
//    heavy-qb-first). Epilogue writes bf16 hi only.
// ---------------------------------------------------------------------------
__global__ __launch_bounds__(256) void k_flash(const unsigned short* __restrict__ qkvh,
                                               const unsigned short* __restrict__ vt,
                                               unsigned short* __restrict__ aoh) {
    __shared__ unsigned short sK[2][64 * 128];
    __shared__ unsigned short sV[2][128 * 64];
    __shared__ unsigned short sP[4][16 * 64];

    const int L = blockIdx.y * gridDim.x + blockIdx.x;
    const int logical = (L & 7) * 128 + (L >> 3);
    const int bh = logical >> 5;
    const int qb = 31 - (logical & 31);
    const int b = bh >> 4, h = bh & 15;

    const int tid = threadIdx.x, wave = tid >> 6, lane = tid & 63;
    const int g = lane >> 4, r16 = lane & 15;
    const float scale = 0.08838834764831845f;   // 1/sqrt(128)

    bf16x8 qf[4];
    {
        const int qrow = qb * 64 + wave * 16 + r16;
        const size_t qbase = ((size_t)(b * TT) + qrow) * QKVN + h * 128;
#pragma unroll
        for (int kk = 0; kk < 4; kk++) {
            ushort8 u = *(const ushort8*)&qkvh[qbase + kk * 32 + g * 8];
            ushort8 o;
#pragma unroll
            for (int e = 0; e < 8; e++) o[e] = f2bf(bf2f(u[e]) * scale);
            qf[kk] = __builtin_bit_cast(bf16x8, o);
        }
    }

    f32x4 oacc[8];
#pragma unroll
    for (int n = 0; n < 8; n++) oacc[n] = (f32x4){0.f, 0.f, 0.f, 0.f};
    float mrun[4], lrun[4];
#pragma unroll
    for (int j = 0; j < 4; j++) { mrun[j] = -1e30f; lrun[j] = 0.f; }

    const int k_row_st = wave * 4 + (lane >> 4);    // + i*16 ; slot = lane&15
    const int v_row_st = wave * 8 + (lane >> 3);    // + i*32 ; slot = lane&7
    const int lidx = wave * 512 + lane * 8;

    auto stage = [&](int buf, int kb) {
#pragma unroll
        for (int i = 0; i < 4; i++) {
            int krow = i * 16 + k_row_st;
            int kcol = ((lane & 15) ^ (krow & 7)) << 3;
            GLOAD16(qkvh + ((size_t)(b * TT + kb * 64 + krow)) * QKVN + 2048 + h * 128 + kcol,
                    &sK[buf][i * 2048 + lidx]);
            int vrow = i * 32 + v_row_st;
            int vcol = ((lane & 7) ^ (vrow & 7)) << 3;
            GLOAD16(vt + ((size_t)bh * 128 + vrow) * TT + kb * 64 + vcol,
                    &sV[buf][i * 2048 + lidx]);
        }
    };

    const int nkb = qb + 1;
    int cur = 0;
    stage(0, 0);

    for (int kb = 0; kb < nkb; kb++) {
        __syncthreads();
        if (kb + 1 < nkb) stage(cur ^ 1, kb + 1);

        f32x4 sacc[4];
#pragma unroll
        for (int n = 0; n < 4; n++) sacc[n] = (f32x4){0.f, 0.f, 0.f, 0.f};
#pragma unroll
        for (int n = 0; n < 4; n++) {
            const int krow = n * 16 + r16;
            const int rbase = krow * 128;
            const int sw = krow & 7;
#pragma unroll
            for (int kk = 0; kk < 4; kk++) {
                int slot = (kk * 4 + g) ^ sw;
                bf16x8 kf = __builtin_bit_cast(bf16x8, *(const ushort8*)&sK[cur][rbase + slot * 8]);
                sacc[n] = __builtin_amdgcn_mfma_f32_16x16x32_bf16(qf[kk], kf, sacc[n], 0, 0, 0);
            }
        }

        const int key0 = kb * 64;
#pragma unroll
        for (int j = 0; j < 4; j++) {
            const int prow = g * 4 + j;
            const int qg = qb * 64 + wave * 16 + prow;
            float s0 = sacc[0][j], s1 = sacc[1][j], s2 = sacc[2][j], s3 = sacc[3][j];
            if (kb == qb) {
                if (key0 + r16 > qg)      s0 = -1e30f;
                if (key0 + 16 + r16 > qg) s1 = -1e30f;
                if (key0 + 32 + r16 > qg) s2 = -1e30f;
                if (key0 + 48 + r16 > qg) s3 = -1e30f;
            }
            float tmax = fmaxf(fmaxf(s0, s1), fmaxf(s2, s3));
#pragma unroll
            for (int off = 8; off >= 1; off >>= 1) tmax = fmaxf(tmax, __shfl_xor(tmax, off));
            float mnew = fmaxf(mrun[j], tmax);
            float corr = __expf(mrun[j] - mnew);
            float p0 = __expf(s0 - mnew), p1 = __expf(s1 - mnew);
            float p2 = __expf(s2 - mnew), p3 = __expf(s3 - mnew);
            float rs = (p0 + p1) + (p2 + p3);
#pragma unroll
            for (int off = 8; off >= 1; off >>= 1) rs += __shfl_xor(rs, off);
            lrun[j] = lrun[j] * corr + rs;
            mrun[j] = mnew;
#pragma unroll
            for (int n = 0; n < 8; n++) oacc[n][j] *= corr;
            const int pb = prow * 64, sw = prow & 7, e = r16 & 7, hi2 = (r16 >> 3);
            sP[wave][pb + (((0 + hi2) ^ sw) << 3) + e] = f2bf(p0);
            sP[wave][pb + (((2 + hi2) ^ sw) << 3) + e] = f2bf(p1);
            sP[wave][pb + (((4 + hi2) ^ sw) << 3) + e] = f2bf(p2);
            sP[wave][pb + (((6 + hi2) ^ sw) << 3) + e] = f2bf(p3);
        }

#pragma unroll
        for (int kk = 0; kk < 2; kk++) {
            const int slot = (kk * 4 + g) ^ (r16 & 7);
            bf16x8 pf = __builtin_bit_cast(bf16x8, *(const ushort8*)&sP[wave][r16 * 64 + slot * 8]);
#pragma unroll
            for (int n = 0; n < 8; n++) {
                const int d = n * 16 + r16;
                bf16x8 vf = __builtin_bit_cast(bf16x8, *(const ushort8*)&sV[cur][d * 64 + slot * 8]);
                oacc[n] = __builtin_amdgcn_mfma_f32_16x16x32_bf16(pf, vf, oacc[n], 0, 0, 0);
            }
        }
        cur ^= 1;
    }

#pragma unroll
    for (int j = 0; j < 4; j++) {
        float inv = 1.0f / lrun[j];
        int qg = qb * 64 + wave * 16 + g * 4 + j;
        size_t obase = ((size_t)(b * TT) + qg) * DM + h * 128;
#pragma unroll
        for (int n = 0; n < 8; n++)
            aoh[obase + n * 16 + r16] = f2bf(oacc[n][j] * inv);
    }
}

// ---------------------------------------------------------------------------
extern "C" void kernel_launch(void* const* d_in, const int* in_sizes, int n_in,
                              void* d_out, int out_size, void* d_ws, size_t ws_size,
                              hipStream_t stream) {
    const float* x = (const float*)d_in[0];
    const float* Wqkv = (const float*)d_in[1];
    const float* Wproj = (const float*)d_in[2];
    const float* bproj = (const float*)d_in[3];
    // d_in[4] = mask (causal structure implemented directly)

    uint8_t* w = (uint8_t*)d_ws;
    auto alloc = [&](size_t bytes) { uint8_t* p = w; w += bytes; return p; };
    unsigned short* xh   = (unsigned short*)alloc(8388608ull * 2);   // x bf16
    unsigned short* wqh  = (unsigned short*)alloc(12582912ull * 2);  // WqkvT [6144][2048]
    unsigned short* wph  = (unsigned short*)alloc(4194304ull * 2);   // WprojT [2048][2048]
    unsigned short* qkvh = (unsigned short*)alloc(25165824ull * 2);  // qkv [4096][6144]
    unsigned short* vtp  = (unsigned short*)alloc(8388608ull * 2);   // V^T [32][128][2048]
    unsigned short* aoh  = (unsigned short*)alloc(8388608ull * 2);   // attn out [4096][2048]

    k_split<<<dim3(8192), dim3(256), 0, stream>>>(x, xh, 2097152);
    k_tsplit<<<dim3(192, 64), dim3(32, 8), 0, stream>>>(Wqkv, wqh, 2048, 6144);
    k_tsplit<<<dim3(64, 64), dim3(32, 8), 0, stream>>>(Wproj, wph, 2048, 2048);
    k_gemm<0, 0><<<dim3(48, 16), dim3(512), 0, stream>>>(xh, nullptr, wqh,
                                                         qkvh, nullptr, nullptr,
                                                         4096, 6144, 2048);
    k_rope<<<dim3(4096), dim3(256), 0, stream>>>(qkvh);
    k_vt<<<dim3(32, 32), dim3(128), 0, stream>>>(qkvh, vtp);
    k_flash<<<dim3(32, 32), dim3(256), 0, stream>>>(qkvh, vtp, aoh);
    k_gemm<1, 0><<<dim3(16, 16), dim3(512), 0, stream>>>(aoh, nullptr, wph,
                                                         nullptr, (float*)d_out, bproj,
                                                         4096, 2048, 2048);
}